// Round 1
// 774.652 us; speedup vs baseline: 1.2148x; 1.2148x over previous
//
#include <hip/hip_runtime.h>
#include <hip/hip_bf16.h>
#include <stdint.h>

// Problem constants (compile-time; shapes fixed by setup_inputs()).
#define M_ROWS 4096      // batch rows of x
#define IN_F   4096      // K
#define OUT_F  11008     // N
#define N_GROUPS 32      // IN_F / 128
#define ALPHA  0.05f

typedef __bf16 bf16;
typedef __bf16 bf16x8 __attribute__((ext_vector_type(8)));
typedef float  floatx4 __attribute__((ext_vector_type(4)));

// async global->LDS, 16B per lane; LDS dest = wave-uniform base + lane*16
__device__ __forceinline__ void async_copy16(const void* g, void* l) {
  __builtin_amdgcn_global_load_lds(
      (const __attribute__((address_space(1))) void*)g,
      (__attribute__((address_space(3))) void*)l, 16, 0, 0);
}

// ---------------------------------------------------------------------------
// Phase 1a: w_noisy[o,i] = (q - zeros[o,g])*scales[o,g] + noise*ALPHA*|w| -> bf16
// ---------------------------------------------------------------------------
__global__ __launch_bounds__(256) void dequant_noise_kernel(
    const int* __restrict__ q, const float* __restrict__ scales,
    const float* __restrict__ zeros, const float* __restrict__ noise,
    bf16* __restrict__ wn) {
  int gid = blockIdx.x * 256 + threadIdx.x;   // 512 threads per output row
  int o = gid >> 9;
  int i = (gid & 511) << 3;                   // 8-aligned -> single group
  int g = i >> 7;
  float s = scales[o * N_GROUPS + g];
  float z = zeros[o * N_GROUPS + g];
  size_t base = (size_t)o * IN_F + i;
  int4   q0 = *(const int4*)(q + base);
  int4   q1 = *(const int4*)(q + base + 4);
  float4 n0 = *(const float4*)(noise + base);
  float4 n1 = *(const float4*)(noise + base + 4);
  float qs[8] = {(float)q0.x, (float)q0.y, (float)q0.z, (float)q0.w,
                 (float)q1.x, (float)q1.y, (float)q1.z, (float)q1.w};
  float ns[8] = {n0.x, n0.y, n0.z, n0.w, n1.x, n1.y, n1.z, n1.w};
  bf16x8 out;
#pragma unroll
  for (int j = 0; j < 8; ++j) {
    float w = (qs[j] - z) * s;
    float v = fmaf(ALPHA * fabsf(w), ns[j], w);   // w + noise*ALPHA*|w|
    out[j] = (bf16)v;
  }
  *(bf16x8*)(wn + base) = out;
}

// ---------------------------------------------------------------------------
// Phase 1b: x fp32 -> bf16
// ---------------------------------------------------------------------------
__global__ __launch_bounds__(256) void xcast_kernel(
    const float* __restrict__ x, bf16* __restrict__ xb) {
  size_t base = ((size_t)blockIdx.x * 256 + threadIdx.x) << 3;
  float4 a0 = *(const float4*)(x + base);
  float4 a1 = *(const float4*)(x + base + 4);
  float vs[8] = {a0.x, a0.y, a0.z, a0.w, a1.x, a1.y, a1.z, a1.w};
  bf16x8 out;
#pragma unroll
  for (int j = 0; j < 8; ++j) out[j] = (bf16)vs[j];
  *(bf16x8*)(xb + base) = out;
}

// ---------------------------------------------------------------------------
// Phase 2: 256x256-tile 8-phase GEMM (T1+T2+T3+T4+T5 port of the m201 template)
//
// C[m][n] = sum_k A[m][k]*W[n][k] + bias[n], A/W bf16 row-major, K inner.
//
// Structure:
//  - 512 threads = 8 waves, 2(M) x 4(N); each wave owns a 128x64 C sub-tile
//    = 8x4 fragments of 16x16, acc = 128 VGPRs.
//  - K is consumed in 32-wide "k-half" pairs P_n (n = 0..127). LDS is a
//    4-deep ring of pair-slots; slot = {A: 256rows x 32k, B: 256rows x 32k}
//    = 32 KiB. Total LDS 128 KiB.
//  - Each pair-slot is computed over 2 phases (16 MFMA each: mi 0-3 then
//    mi 4-7, ni 0-3, K=32). Phase 1 reads 8x ds_read_b128 (A mi0-3 + all B),
//    phase 2 reads 4 (A mi4-7; B reused from regs).
//  - Pair n's phases stage P_{n+3} into slot (n+3)&3 (= slot freed when
//    P_{n-1} finished one barrier earlier -> write-after-read safe).
//    Phase 1 stages the A half (2 gload_lds/thread), phase 2 the B half.
//  - Counted vmcnt: before entering pair n, all waves passed
//    "s_waitcnt vmcnt(8); s_barrier" at the end of pair n-1. Outstanding
//    loads there are P_{n+1}(4) + P_{n+2}(4) + P_n(4, oldest); FIFO vmem
//    retirement => vmcnt(8) proves P_n landed, while 8 loads keep flying
//    across the barrier (never drain to 0 in the main loop).
//
// LDS swizzle (derived for 64 B k-half rows; bank-verified conflict-free):
//  logical (row r, 8-elem chunk kc) -> byte off = (r>>1)*128 + pc*16,
//  pc = (((r&1)<<2)|kc) ^ ((r>>1)&7). gload_lds writes linearly
//  (base + lane*16), so the swizzle is realized by permuting each lane's
//  GLOBAL source (m173 pattern): lane ln of instr (wv,j) fetches
//  row = (wv*2+j)*16 + (ln>>3)*2 + (dec>>2), kc = dec&3, dec=(ln&7)^(ln>>3).
//  Fragment read: lane(frow=ln&15, g4=ln>>4) reads r = base+frow, kc=g4 ->
//  every 8-lane phase of ds_read_b128 hits all 32 banks exactly once.
// ---------------------------------------------------------------------------
#define NH (IN_F / 32)   // 128 k-halves

__global__ __launch_bounds__(512, 2) void gemm_8ph_kernel(
    const bf16* __restrict__ A,    // [M_ROWS][IN_F]
    const bf16* __restrict__ W,    // [OUT_F][IN_F]
    const float* __restrict__ bias,
    float* __restrict__ C) {       // [M_ROWS][OUT_F]
  __shared__ bf16 lds[4 * 16384];  // 4 pair-slots x (A 8192 + B 8192) elems

  const int tid = threadIdx.x;
  const int wv = tid >> 6;          // wave 0..7
  const int ln = tid & 63;
  const int wr = wv >> 2;           // wave M row (0..1) -> rows wr*128..+128
  const int wc = wv & 3;            // wave N col (0..3) -> cols wc*64..+64

  // XCD-bijective swizzle (688 = 8*86) + m-pair supertile: each XCD sweeps
  // bn with 2 resident A panels (4 MB, L2-fits); all XCDs share B via L3.
  const int orig = blockIdx.x;
  const int idx  = orig >> 3;                    // 0..85
  const int bm   = ((orig & 7) << 1) | (idx & 1);
  const int bn   = idx >> 1;
  const int mbase = bm << 8;
  const int nbase = bn << 8;

  // Staging source (per-lane pre-swizzled global address; LDS dest linear).
  const int dec    = (ln & 7) ^ (ln >> 3);
  const int rstage = wv * 32 + (ln >> 3) * 2 + (dec >> 2);  // j=0 row; j=1 +16
  const int kcol   = (dec & 3) * 8;
  const bf16* aS = A + (size_t)(mbase + rstage) * IN_F + kcol;
  const bf16* bS = W + (size_t)(nbase + rstage) * IN_F + kcol;

  // Fragment ds_read offsets (elements).
  const int frow = ln & 15;
  const int g4   = ln >> 4;
  const int pc   = (((frow & 1) << 2) | g4) ^ (frow >> 1);
  const int aoff = (wr * 64 + (frow >> 1)) * 64 + pc * 8;          // + mi*512
  const int boff = 8192 + (wc * 32 + (frow >> 1)) * 64 + pc * 8;   // + ni*512

  floatx4 acc[8][4] = {};

#define STAGE_A(DST, KH)                                                          \
  do {                                                                            \
    async_copy16(aS + (size_t)(KH) * 32,             &lds[(DST) * 16384 + wv * 1024]);        \
    async_copy16(aS + (size_t)(KH) * 32 + 16 * IN_F, &lds[(DST) * 16384 + wv * 1024 + 512]);  \
  } while (0)
#define STAGE_B(DST, KH)                                                          \
  do {                                                                            \
    async_copy16(bS + (size_t)(KH) * 32,             &lds[(DST) * 16384 + 8192 + wv * 1024]);       \
    async_copy16(bS + (size_t)(KH) * 32 + 16 * IN_F, &lds[(DST) * 16384 + 8192 + wv * 1024 + 512]); \
  } while (0)

  // Prologue: stage P0,P1,P2 (12 loads). vmcnt(8) -> oldest 4 (P0) landed.
  STAGE_A(0, 0); STAGE_B(0, 0);
  STAGE_A(1, 1); STAGE_B(1, 1);
  STAGE_A(2, 2); STAGE_B(2, 2);
  asm volatile("s_waitcnt vmcnt(8)" ::: "memory");
  __builtin_amdgcn_s_barrier();

#define PAIR(SLOT, KH, DO_STAGE, TVM)                                             \
  {                                                                               \
    bf16x8 afr[4], bfr[4], afr2[4];                                               \
    _Pragma("unroll") for (int mi = 0; mi < 4; ++mi)                              \
      afr[mi] = *(const bf16x8*)&lds[(SLOT) * 16384 + aoff + mi * 512];           \
    _Pragma("unroll") for (int ni = 0; ni < 4; ++ni)                              \
      bfr[ni] = *(const bf16x8*)&lds[(SLOT) * 16384 + boff + ni * 512];           \
    if (DO_STAGE) STAGE_A(((SLOT) + 3) & 3, (KH) + 3);                            \
    __builtin_amdgcn_s_barrier();                                                 \
    asm volatile("s_waitcnt lgkmcnt(0)" ::: "memory");                            \
    __builtin_amdgcn_s_setprio(1);                                                \
    _Pragma("unroll") for (int mi = 0; mi < 4; ++mi)                              \
      _Pragma("unroll") for (int ni = 0; ni < 4; ++ni)                            \
        acc[mi][ni] = __builtin_amdgcn_mfma_f32_16x16x32_bf16(                    \
            afr[mi], bfr[ni], acc[mi][ni], 0, 0, 0);                              \
    __builtin_amdgcn_s_setprio(0);                                                \
    __builtin_amdgcn_s_barrier();                                                 \
    _Pragma("unroll") for (int mi = 0; mi < 4; ++mi)                              \
      afr2[mi] = *(const bf16x8*)&lds[(SLOT) * 16384 + aoff + (4 + mi) * 512];    \
    if (DO_STAGE) STAGE_B(((SLOT) + 3) & 3, (KH) + 3);                            \
    __builtin_amdgcn_s_barrier();                                                 \
    asm volatile("s_waitcnt lgkmcnt(0)" ::: "memory");                            \
    __builtin_amdgcn_s_setprio(1);                                                \
    _Pragma("unroll") for (int mi = 0; mi < 4; ++mi)                              \
      _Pragma("unroll") for (int ni = 0; ni < 4; ++ni)                            \
        acc[4 + mi][ni] = __builtin_amdgcn_mfma_f32_16x16x32_bf16(                \
            afr2[mi], bfr[ni], acc[4 + mi][ni], 0, 0, 0);                         \
    __builtin_amdgcn_s_setprio(0);                                                \
    asm volatile("s_waitcnt " TVM ::: "memory");                                  \
    __builtin_amdgcn_s_barrier();                                                 \
  }

  // Main loop: 31 ring revolutions (pairs 0..123), all staging P_{n+3}.
  for (int kh = 0; kh < 124; kh += 4) {
    PAIR(0, kh + 0, true, "vmcnt(8)");
    PAIR(1, kh + 1, true, "vmcnt(8)");
    PAIR(2, kh + 2, true, "vmcnt(8)");
    PAIR(3, kh + 3, true, "vmcnt(8)");
  }
  // Tail: pair 124 still stages P_127; then drain 8 -> 4 -> 0.
  PAIR(0, 124, true,  "vmcnt(8)");
  PAIR(1, 125, false, "vmcnt(4)");
  PAIR(2, 126, false, "vmcnt(0)");
  PAIR(3, 127, false, "vmcnt(0)");

#undef PAIR
#undef STAGE_A
#undef STAGE_B

  // Epilogue. C/D layout (m89-verified): col = lane&15, row = (lane>>4)*4 + reg.
#pragma unroll
  for (int ni = 0; ni < 4; ++ni) {
    int n = nbase + wc * 64 + ni * 16 + (ln & 15);
    float bv = bias[n];
#pragma unroll
    for (int mi = 0; mi < 8; ++mi) {
      int m0 = mbase + wr * 128 + mi * 16 + (ln >> 4) * 4;
#pragma unroll
      for (int r = 0; r < 4; ++r)
        C[(size_t)(m0 + r) * OUT_F + n] = acc[mi][ni][r] + bv;
    }
  }
}

// ---------------------------------------------------------------------------
extern "C" void kernel_launch(void* const* d_in, const int* in_sizes, int n_in,
                              void* d_out, int out_size, void* d_ws, size_t ws_size,
                              hipStream_t stream) {
  const float* x       = (const float*)d_in[0];  // [4096][4096]
  const int*   qweight = (const int*)d_in[1];    // [11008][4096]
  const float* scales  = (const float*)d_in[2];  // [11008][32]
  const float* zeros   = (const float*)d_in[3];  // [11008][32]
  const float* bias    = (const float*)d_in[4];  // [11008]
  const float* noise   = (const float*)d_in[5];  // [11008][4096]
  float* out = (float*)d_out;                    // [4096][11008]

  // Workspace layout: wn bf16 [OUT_F][IN_F] (90.2 MB), then xb bf16 (33.6 MB).
  bf16* wn = (bf16*)d_ws;
  bf16* xb = (bf16*)((char*)d_ws + (size_t)OUT_F * IN_F * sizeof(bf16));

  // Phase 1: materialize noisy weights + bf16 x (fully rewritten every call).
  dequant_noise_kernel<<<(OUT_F * (IN_F / 8)) / 256, 256, 0, stream>>>(
      qweight, scales, zeros, noise, wn);
  xcast_kernel<<<(M_ROWS * (IN_F / 8)) / 256, 256, 0, stream>>>(x, xb);

  // Phase 2: 256x256-tile 8-phase bf16 MFMA GEMM.
  // Grid: (11008/256)*(4096/256) = 43*16 = 688 = 8 XCDs * 86.
  gemm_8ph_kernel<<<dim3(688), 512, 0, stream>>>(xb, wn, bias, out);
}